// Round 3
// baseline (380.963 us; speedup 1.0000x reference)
//
#include <hip/hip_runtime.h>

typedef _Float16 f16x8 __attribute__((ext_vector_type(8)));
typedef _Float16 f16x4 __attribute__((ext_vector_type(4)));
typedef float f32x4 __attribute__((ext_vector_type(4)));
typedef float f32x16 __attribute__((ext_vector_type(16)));

#define BN_EPS 1e-5f
#define SQRT32 5.656854249492381f

// ---------------------------------------------------------------- prep_x
// x [b][c=384][n=1024] fp32 -> xT_hi/xT_lo [b][n=1024][c=384] fp16 planes.
__global__ __launch_bounds__(256) void prep_x(const float* __restrict__ x,
                                              _Float16* __restrict__ xT_hi,
                                              _Float16* __restrict__ xT_lo) {
    __shared__ float Tx[64][65];
    const int ct = blockIdx.x, nt = blockIdx.y, b = blockIdx.z;
    const int c0 = ct * 64, n0 = nt * 64, t = threadIdx.x;
    {
        int tr = t >> 4, tc = (t & 15) * 4;
        #pragma unroll
        for (int p = 0; p < 4; p++) {
            int r = tr + p * 16;
            float4 v = *(const float4*)(x + ((size_t)(b * 384 + c0 + r)) * 1024 + n0 + tc);
            Tx[r][tc + 0] = v.x; Tx[r][tc + 1] = v.y; Tx[r][tc + 2] = v.z; Tx[r][tc + 3] = v.w;
        }
    }
    __syncthreads();
    {
        int nn = t >> 2, cc = (t & 3) * 16;
        f16x8 h0, h1, l0, l1;
        #pragma unroll
        for (int i = 0; i < 8; i++) {
            float v = Tx[cc + i][nn];
            _Float16 hh = (_Float16)v;
            h0[i] = hh; l0[i] = (_Float16)(v - (float)hh);
        }
        #pragma unroll
        for (int i = 0; i < 8; i++) {
            float v = Tx[cc + 8 + i][nn];
            _Float16 hh = (_Float16)v;
            h1[i] = hh; l1[i] = (_Float16)(v - (float)hh);
        }
        size_t o = ((size_t)(b * 1024 + n0 + nn)) * 384 + c0 + cc;
        *(f16x8*)(xT_hi + o) = h0; *(f16x8*)(xT_hi + o + 8) = h1;
        *(f16x8*)(xT_lo + o) = l0; *(f16x8*)(xT_lo + o + 8) = l1;
    }
}

// ---------------------------------------------------------------- prep_w
__global__ __launch_bounds__(256) void prep_w(const float* __restrict__ wq,
                                              const float* __restrict__ wk,
                                              const float* __restrict__ wv,
                                              const float* __restrict__ wp,
                                              _Float16* __restrict__ wqk_h,
                                              _Float16* __restrict__ wqk_l,
                                              _Float16* __restrict__ wv_h,
                                              _Float16* __restrict__ wp_h) {
    const int NQK = 512 * 384, NV = 1024 * 384, NP = 384 * 1024;
    int i = blockIdx.x * 256 + threadIdx.x;
    if (i < NQK) {
        int o = i / 384, c = i - o * 384;
        float v = (o < 256) ? wq[o * 384 + c] : wk[(o - 256) * 384 + c];
        _Float16 hh = (_Float16)v;
        wqk_h[i] = hh; wqk_l[i] = (_Float16)(v - (float)hh);
    } else if (i < NQK + NV) {
        wv_h[i - NQK] = (_Float16)wv[i - NQK];
    } else if (i < NQK + NV + NP) {
        wp_h[i - NQK - NV] = (_Float16)wp[i - NQK - NV];
    }
}

// ---------------------------------------------------------------- prep_st
__global__ __launch_bounds__(256) void prep_st(const float* __restrict__ bnq,
                                               const float* __restrict__ bnk,
                                               const float* __restrict__ bnv,
                                               const float* __restrict__ bnp,
                                               float* __restrict__ s_qkv, float* __restrict__ t_qkv,
                                               float* __restrict__ s_p,   float* __restrict__ t_p) {
    int i = blockIdx.x * blockDim.x + threadIdx.x;
    if (i < 1536) {
        float g, be, m, v;
        if (i < 256)      { int o = i;       g = bnq[o]; be = bnq[256 + o];  m = bnq[512 + o];  v = bnq[768 + o]; }
        else if (i < 512) { int o = i - 256; g = bnk[o]; be = bnk[256 + o];  m = bnk[512 + o];  v = bnk[768 + o]; }
        else              { int o = i - 512; g = bnv[o]; be = bnv[1024 + o]; m = bnv[2048 + o]; v = bnv[3072 + o]; }
        float s = g * rsqrtf(v + BN_EPS);
        float t = be - m * s;
        if (i < 256) { s *= SQRT32; t *= SQRT32; }   // fold /scale (= *sqrt(kd)) into Q
        s_qkv[i] = s; t_qkv[i] = t;
    } else if (i < 1536 + 384) {
        int o = i - 1536;
        float g = bnp[o], be = bnp[384 + o], m = bnp[768 + o], v = bnp[1152 + o];
        float s = g * rsqrtf(v + BN_EPS);
        s_p[o] = s; t_p[o] = be - m * s;
    }
}

// ---------------------------------------------------------------- gemm_qkv
// D[o][n] = sum_c W[o,c] X[c,n].  bx<4: Q/K rows (3-term hi/lo, fp32 out)
// bx>=4: V rows (1-term, fp16 out).
__global__ __launch_bounds__(256, 2) void gemm_qkv(
    const _Float16* __restrict__ wqk_h, const _Float16* __restrict__ wqk_l,
    const _Float16* __restrict__ wv_h,
    const _Float16* __restrict__ xT_hi, const _Float16* __restrict__ xT_lo,
    const float* __restrict__ S, const float* __restrict__ T,
    float* __restrict__ qf, float* __restrict__ kf, _Float16* __restrict__ vbuf)
{
    __shared__ __align__(16) _Float16 As_h[128 * 40];
    __shared__ __align__(16) _Float16 As_l[128 * 40];
    __shared__ __align__(16) _Float16 Bs_h[128 * 40];
    __shared__ __align__(16) _Float16 Bs_l[128 * 40];
    const int t = threadIdx.x, lane = t & 63, w = t >> 6;
    const int wr = w >> 1, wc = w & 1, l16 = lane & 15, lq = lane >> 4;
    const int bx = blockIdx.x, n0 = blockIdx.y * 128, b = blockIdx.z;
    const bool isv = bx >= 4;
    const int o0 = isv ? (bx - 4) * 128 : bx * 128;
    const _Float16* __restrict__ Ah = isv ? wv_h : wqk_h;

    f32x4 acc[4][4] = {};

    for (int kb = 0; kb < 384; kb += 32) {
        __syncthreads();
        #pragma unroll
        for (int p = 0; p < 2; p++) {
            int g = t + p * 256, row = g >> 2, ch = g & 3;
            *(uint4*)(&As_h[row * 40 + ch * 8]) =
                *(const uint4*)(Ah + (size_t)(o0 + row) * 384 + kb + ch * 8);
        }
        #pragma unroll
        for (int p = 0; p < 2; p++) {
            int g = t + p * 256, row = g >> 2, ch = g & 3;
            *(uint4*)(&Bs_h[row * 40 + ch * 8]) =
                *(const uint4*)(xT_hi + ((size_t)(b * 1024) + n0 + row) * 384 + kb + ch * 8);
        }
        if (!isv) {
            #pragma unroll
            for (int p = 0; p < 2; p++) {
                int g = t + p * 256, row = g >> 2, ch = g & 3;
                *(uint4*)(&As_l[row * 40 + ch * 8]) =
                    *(const uint4*)(wqk_l + (size_t)(o0 + row) * 384 + kb + ch * 8);
            }
            #pragma unroll
            for (int p = 0; p < 2; p++) {
                int g = t + p * 256, row = g >> 2, ch = g & 3;
                *(uint4*)(&Bs_l[row * 40 + ch * 8]) =
                    *(const uint4*)(xT_lo + ((size_t)(b * 1024) + n0 + row) * 384 + kb + ch * 8);
            }
        }
        __syncthreads();

        f16x8 ah[4], bh[4];
        #pragma unroll
        for (int i = 0; i < 4; i++) ah[i] = *(const f16x8*)(&As_h[(wr * 64 + i * 16 + l16) * 40 + lq * 8]);
        #pragma unroll
        for (int j = 0; j < 4; j++) bh[j] = *(const f16x8*)(&Bs_h[(wc * 64 + j * 16 + l16) * 40 + lq * 8]);
        if (!isv) {
            f16x8 al[4], bl[4];
            #pragma unroll
            for (int i = 0; i < 4; i++) al[i] = *(const f16x8*)(&As_l[(wr * 64 + i * 16 + l16) * 40 + lq * 8]);
            #pragma unroll
            for (int j = 0; j < 4; j++) bl[j] = *(const f16x8*)(&Bs_l[(wc * 64 + j * 16 + l16) * 40 + lq * 8]);
            #pragma unroll
            for (int i = 0; i < 4; i++)
                #pragma unroll
                for (int j = 0; j < 4; j++) {
                    acc[i][j] = __builtin_amdgcn_mfma_f32_16x16x32_f16(ah[i], bh[j], acc[i][j], 0, 0, 0);
                    acc[i][j] = __builtin_amdgcn_mfma_f32_16x16x32_f16(al[i], bh[j], acc[i][j], 0, 0, 0);
                    acc[i][j] = __builtin_amdgcn_mfma_f32_16x16x32_f16(ah[i], bl[j], acc[i][j], 0, 0, 0);
                }
        } else {
            #pragma unroll
            for (int i = 0; i < 4; i++)
                #pragma unroll
                for (int j = 0; j < 4; j++)
                    acc[i][j] = __builtin_amdgcn_mfma_f32_16x16x32_f16(ah[i], bh[j], acc[i][j], 0, 0, 0);
        }
    }

    if (!isv) {
        #pragma unroll
        for (int i = 0; i < 4; i++) {
            #pragma unroll
            for (int r = 0; r < 4; r++) {
                int o = o0 + wr * 64 + i * 16 + lq * 4 + r;
                float sc = S[o], sh = T[o];
                float* dst = (o < 256) ? (qf + ((size_t)(b * 256) + o) * 1024)
                                       : (kf + ((size_t)(b * 256) + o - 256) * 1024);
                #pragma unroll
                for (int j = 0; j < 4; j++) {
                    int n = n0 + wc * 64 + j * 16 + l16;
                    dst[n] = acc[i][j][r] * sc + sh;
                }
            }
        }
    } else {
        #pragma unroll
        for (int i = 0; i < 4; i++) {
            #pragma unroll
            for (int r = 0; r < 4; r++) {
                int o = o0 + wr * 64 + i * 16 + lq * 4 + r;
                float sc = S[512 + o], sh = T[512 + o];
                #pragma unroll
                for (int j = 0; j < 4; j++) {
                    int n = n0 + wc * 64 + j * 16 + l16;
                    vbuf[((size_t)(b * 1024) + o) * 1024 + n] = (_Float16)(acc[i][j][r] * sc + sh);
                }
            }
        }
    }
}

// ---------------------------------------------------------------- transpose_k
// kf [b][256][1024] fp32 -> kT_h/kT_l [b][h][n=1024][kd=32] fp16 planes.
__global__ __launch_bounds__(256) void transpose_k(const float* __restrict__ kf,
                                                   _Float16* __restrict__ kT_h,
                                                   _Float16* __restrict__ kT_l) {
    __shared__ float Tk[32][65];
    const int nt = blockIdx.x, h = blockIdx.y, b = blockIdx.z;
    const int n0 = nt * 64, t = threadIdx.x;
    {
        int r = t >> 3, ch = (t & 7) * 8;
        const float* src = kf + ((size_t)(b * 256) + h * 32 + r) * 1024 + n0 + ch;
        float4 v0 = *(const float4*)src, v1 = *(const float4*)(src + 4);
        Tk[r][ch + 0] = v0.x; Tk[r][ch + 1] = v0.y; Tk[r][ch + 2] = v0.z; Tk[r][ch + 3] = v0.w;
        Tk[r][ch + 4] = v1.x; Tk[r][ch + 5] = v1.y; Tk[r][ch + 6] = v1.z; Tk[r][ch + 7] = v1.w;
    }
    __syncthreads();
    {
        int nn = t >> 2, c0 = (t & 3) * 8;
        f16x8 hv, lv;
        #pragma unroll
        for (int i = 0; i < 8; i++) {
            float v = Tk[c0 + i][nn];
            _Float16 hh = (_Float16)v;
            hv[i] = hh; lv[i] = (_Float16)(v - (float)hh);
        }
        size_t o = (((size_t)(b * 8) + h) * 1024 + n0 + nn) * 32 + c0;
        *(f16x8*)(kT_h + o) = hv;
        *(f16x8*)(kT_l + o) = lv;
    }
}

// ---------------------------------------------------------------- attn
// Grid: (x=bh [128], y=qt [8]) so all q-tiles of one (b,h) land on one XCD
// (linear_id % 8 == bh % 8) -> K/V stay resident in that XCD's L2.
// Per block: 128 queries (4 waves x 32), online softmax over 16 tiles of 64 keys.
// K tile (hi+lo) AND V tile staged in LDS (coalesced, once per block per kt).
// Scores computed transposed: D[key][query] (A=K, B=Q), 3-term hi/lo.
// PV via mfma 32x32x8: P C-layout regs map directly onto B-operand (no repack).
__global__ __launch_bounds__(256, 4) void attn(
    const float* __restrict__ qf,
    const _Float16* __restrict__ kT_h, const _Float16* __restrict__ kT_l,
    const _Float16* __restrict__ vbuf,
    _Float16* __restrict__ xxT_h, _Float16* __restrict__ xxT_l)
{
    __shared__ __align__(16) _Float16 Ks_h[64 * 36];
    __shared__ __align__(16) _Float16 Ks_l[64 * 36];
    __shared__ __align__(16) _Float16 Vs[128 * 72];
    const int t = threadIdx.x, lane = t & 63, w = t >> 6;
    const int L = lane & 31, hl = lane >> 5;
    const int bh = blockIdx.x, qt = blockIdx.y;
    const int b = bh >> 3, h = bh & 7;
    const int q = qt * 128 + w * 32 + L;

    // Q B-frags: fp32 -> hi/lo split in-register (once per kernel; lane-coalesced)
    f16x8 bq_h[2], bq_l[2];
    #pragma unroll
    for (int kh = 0; kh < 2; kh++) {
        #pragma unroll
        for (int i = 0; i < 8; i++) {
            float v = qf[((size_t)(b * 256) + h * 32 + kh * 16 + hl * 8 + i) * 1024 + q];
            _Float16 hh = (_Float16)v;
            bq_h[kh][i] = hh;
            bq_l[kh][i] = (_Float16)(v - (float)hh);
        }
    }

    f32x16 o_acc[4] = {};
    float m_st = -INFINITY, l_st = 0.f;

    // per-thread staging coords
    const int krow = t >> 2, kcol = (t & 3) * 8;              // K: 64 rows x 32 (16B/thread/plane)

    for (int kt = 0; kt < 16; kt++) {
        __syncthreads();
        {   // stage K tile [64 keys][32 kd] hi+lo (pad 36 halves -> conflict-free quarters)
            size_t src = ((size_t)(bh * 1024) + kt * 64 + krow) * 32 + kcol;
            *(uint4*)(&Ks_h[krow * 36 + kcol]) = *(const uint4*)(kT_h + src);
            *(uint4*)(&Ks_l[krow * 36 + kcol]) = *(const uint4*)(kT_l + src);
        }
        #pragma unroll
        for (int p = 0; p < 4; p++) {   // stage V tile [128 d][64 keys], granule-rotated
            int g = t + p * 256, d = g >> 3, kc = g & 7;
            int kc2 = (kc + (d >> 3)) & 7;
            *(uint4*)(&Vs[d * 72 + kc2 * 8]) =
                *(const uint4*)(vbuf + ((size_t)(b * 1024) + h * 128 + d) * 1024 + kt * 64 + kc * 8);
        }
        __syncthreads();

        // scores S^T[key][query], 3-term hi/lo; K frags from LDS
        f32x16 sA[2];
        #pragma unroll
        for (int sub = 0; sub < 2; sub++) {
            f32x16 c = {};
            #pragma unroll
            for (int kh = 0; kh < 2; kh++) {
                int kr = (sub * 32 + L) * 36 + kh * 16 + hl * 8;
                f16x8 k_h = *(const f16x8*)(&Ks_h[kr]);
                f16x8 k_l = *(const f16x8*)(&Ks_l[kr]);
                c = __builtin_amdgcn_mfma_f32_32x32x16_f16(k_h, bq_h[kh], c, 0, 0, 0);
                c = __builtin_amdgcn_mfma_f32_32x32x16_f16(k_l, bq_h[kh], c, 0, 0, 0);
                c = __builtin_amdgcn_mfma_f32_32x32x16_f16(k_h, bq_l[kh], c, 0, 0, 0);
            }
            sA[sub] = c;
        }

        // online softmax (per-lane scalars; 2 cross-lane shuffles per tile)
        float mx = -INFINITY;
        #pragma unroll
        for (int i = 0; i < 16; i++) mx = fmaxf(mx, fmaxf(sA[0][i], sA[1][i]));
        mx = fmaxf(mx, __shfl_xor(mx, 32, 64));
        float mnew = fmaxf(m_st, mx);
        float alpha = __expf(m_st - mnew);
        float rs = 0.f;
        f16x4 pfrag[8];
        #pragma unroll
        for (int sub = 0; sub < 2; sub++)
            #pragma unroll
            for (int qq = 0; qq < 4; qq++)
                #pragma unroll
                for (int rr = 0; rr < 4; rr++) {
                    float p = __expf(sA[sub][qq * 4 + rr] - mnew);
                    rs += p;
                    pfrag[sub * 4 + qq][rr] = (_Float16)p;
                }
        rs += __shfl_xor(rs, 32, 64);
        l_st = l_st * alpha + rs;
        m_st = mnew;
        #pragma unroll
        for (int dt = 0; dt < 4; dt++)
            #pragma unroll
            for (int i = 0; i < 16; i++) o_acc[dt][i] *= alpha;

        // O[d][query] += V * P  (32 x mfma 32x32x8, zero P repack)
        #pragma unroll
        for (int sub = 0; sub < 2; sub++) {
            #pragma unroll
            for (int qq = 0; qq < 4; qq++) {
                f16x4 bp = pfrag[sub * 4 + qq];
                #pragma unroll
                for (int dt = 0; dt < 4; dt++) {
                    int kc2 = ((sub * 4 + qq) + dt * 4 + (L >> 3)) & 7;
                    f16x4 av = *(const f16x4*)(&Vs[(dt * 32 + L) * 72 + kc2 * 8 + hl * 4]);
                    o_acc[dt] = __builtin_amdgcn_mfma_f32_32x32x8f16(av, bp, o_acc[dt], 0, 0, 0);
                }
            }
        }
    }

    // epilogue: normalize, split hi/lo, store xxT[b][n=q][d] (d contiguous)
    float rl = 1.f / l_st;
    #pragma unroll
    for (int dt = 0; dt < 4; dt++) {
        #pragma unroll
        for (int g = 0; g < 4; g++) {
            f16x4 hv, lv;
            #pragma unroll
            for (int rr = 0; rr < 4; rr++) {
                float v = o_acc[dt][g * 4 + rr] * rl;
                _Float16 hh = (_Float16)v;
                hv[rr] = hh; lv[rr] = (_Float16)(v - (float)hh);
            }
            size_t o = ((size_t)(b * 1024) + q) * 1024 + h * 128 + dt * 32 + g * 8 + hl * 4;
            *(f16x4*)(xxT_h + o) = hv;
            *(f16x4*)(xxT_l + o) = lv;
        }
    }
}

// ---------------------------------------------------------------- gemm_out
// out[o][n] = (sum_c Wp[o,c]*xx[c,n]) * s + t, 2-term hi/lo on xx. fp32 out.
__global__ __launch_bounds__(256, 2) void gemm_out(
    const _Float16* __restrict__ wp_h,
    const _Float16* __restrict__ xxT_h, const _Float16* __restrict__ xxT_l,
    const float* __restrict__ S, const float* __restrict__ T,
    float* __restrict__ out)
{
    __shared__ __align__(16) _Float16 As[128 * 40];
    __shared__ __align__(16) _Float16 Bh[64 * 40];
    __shared__ __align__(16) _Float16 Bl[64 * 40];
    const int t = threadIdx.x, lane = t & 63, w = t >> 6;
    const int wr = w >> 1, wc = w & 1, l16 = lane & 15, lq = lane >> 4;
    const int o0 = blockIdx.x * 128, n0 = blockIdx.y * 64, b = blockIdx.z;

    f32x4 acc[4][2] = {};

    for (int kb = 0; kb < 1024; kb += 32) {
        __syncthreads();
        #pragma unroll
        for (int p = 0; p < 2; p++) {
            int g = t + p * 256, row = g >> 2, ch = g & 3;
            *(uint4*)(&As[row * 40 + ch * 8]) =
                *(const uint4*)(wp_h + (size_t)(o0 + row) * 1024 + kb + ch * 8);
        }
        {
            int row = t >> 2, ch = t & 3;
            size_t src = ((size_t)(b * 1024) + n0 + row) * 1024 + kb + ch * 8;
            *(uint4*)(&Bh[row * 40 + ch * 8]) = *(const uint4*)(xxT_h + src);
            *(uint4*)(&Bl[row * 40 + ch * 8]) = *(const uint4*)(xxT_l + src);
        }
        __syncthreads();

        f16x8 a[4], bh[2], bl[2];
        #pragma unroll
        for (int i = 0; i < 4; i++) a[i] = *(const f16x8*)(&As[(wr * 64 + i * 16 + l16) * 40 + lq * 8]);
        #pragma unroll
        for (int j = 0; j < 2; j++) {
            bh[j] = *(const f16x8*)(&Bh[(wc * 32 + j * 16 + l16) * 40 + lq * 8]);
            bl[j] = *(const f16x8*)(&Bl[(wc * 32 + j * 16 + l16) * 40 + lq * 8]);
        }
        #pragma unroll
        for (int i = 0; i < 4; i++)
            #pragma unroll
            for (int j = 0; j < 2; j++) {
                acc[i][j] = __builtin_amdgcn_mfma_f32_16x16x32_f16(a[i], bh[j], acc[i][j], 0, 0, 0);
                acc[i][j] = __builtin_amdgcn_mfma_f32_16x16x32_f16(a[i], bl[j], acc[i][j], 0, 0, 0);
            }
    }

    #pragma unroll
    for (int i = 0; i < 4; i++) {
        #pragma unroll
        for (int r = 0; r < 4; r++) {
            int o = o0 + wr * 64 + i * 16 + lq * 4 + r;
            float sc = S[o], sh = T[o];
            #pragma unroll
            for (int j = 0; j < 2; j++) {
                int n = n0 + wc * 32 + j * 16 + l16;
                out[((size_t)(b * 384) + o) * 1024 + n] = acc[i][j][r] * sc + sh;
            }
        }
    }
}

// ---------------------------------------------------------------- launch

extern "C" void kernel_launch(void* const* d_in, const int* in_sizes, int n_in,
                              void* d_out, int out_size, void* d_ws, size_t ws_size,
                              hipStream_t stream) {
    const float* x   = (const float*)d_in[0];
    const float* wq  = (const float*)d_in[1];
    const float* bnq = (const float*)d_in[2];
    const float* wk  = (const float*)d_in[3];
    const float* bnk = (const float*)d_in[4];
    const float* wv  = (const float*)d_in[5];
    const float* bnv = (const float*)d_in[6];
    const float* wp  = (const float*)d_in[7];
    const float* bnp = (const float*)d_in[8];
    float* out = (float*)d_out;
    (void)in_sizes; (void)n_in; (void)out_size; (void)ws_size;

    char* ws = (char*)d_ws;
    size_t off = 0;
    auto alloc = [&](size_t bytes) {
        void* p = ws + off;
        off = (off + bytes + 255) & ~(size_t)255;
        return p;
    };
    // --- region dead by attn-time (reused for xxT_h) ---
    _Float16* xT_hi = (_Float16*)alloc((size_t)16 * 1024 * 384 * 2);   // 12.58 MB
    _Float16* xT_lo = (_Float16*)alloc((size_t)16 * 1024 * 384 * 2);   // 12.58 MB
    _Float16* wqk_h = (_Float16*)alloc((size_t)512 * 384 * 2);
    _Float16* wqk_l = (_Float16*)alloc((size_t)512 * 384 * 2);
    _Float16* wv_h  = (_Float16*)alloc((size_t)1024 * 384 * 2);
    float*    kf    = (float*)alloc((size_t)16 * 256 * 1024 * 4);      // 16.78 MB
    // region total ~43.5 MB >= xxT_h (33.55 MB)
    _Float16* xxT_h = (_Float16*)d_ws;                                  // alias over dead region
    // --- live buffers ---
    _Float16* wp_h  = (_Float16*)alloc((size_t)384 * 1024 * 2);
    float*    s_qkv = (float*)alloc(1536 * 4);
    float*    t_qkv = (float*)alloc(1536 * 4);
    float*    s_p   = (float*)alloc(384 * 4);
    float*    t_p   = (float*)alloc(384 * 4);
    float*    qf    = (float*)alloc((size_t)16 * 256 * 1024 * 4);      // 16.78 MB
    _Float16* kT_h  = (_Float16*)alloc((size_t)16 * 8 * 1024 * 32 * 2);// 8.39 MB
    _Float16* kT_l  = (_Float16*)alloc((size_t)16 * 8 * 1024 * 32 * 2);// 8.39 MB
    _Float16* vbuf  = (_Float16*)alloc((size_t)16 * 1024 * 1024 * 2);  // 33.55 MB
    _Float16* xxT_l = (_Float16*)alloc((size_t)16 * 1024 * 1024 * 2);  // 33.55 MB

    prep_x<<<dim3(6, 16, 16), dim3(256), 0, stream>>>(x, xT_hi, xT_lo);
    {
        int total = 512 * 384 + 1024 * 384 + 384 * 1024;
        prep_w<<<dim3((total + 255) / 256), dim3(256), 0, stream>>>(wq, wk, wv, wp,
                                                                    wqk_h, wqk_l, wv_h, wp_h);
    }
    prep_st<<<dim3(8), dim3(256), 0, stream>>>(bnq, bnk, bnv, bnp, s_qkv, t_qkv, s_p, t_p);

    gemm_qkv<<<dim3(12, 8, 16), dim3(256), 0, stream>>>(wqk_h, wqk_l, wv_h, xT_hi, xT_lo,
                                                        s_qkv, t_qkv, qf, kf, vbuf);
    transpose_k<<<dim3(16, 8, 16), dim3(256), 0, stream>>>(kf, kT_h, kT_l);
    attn<<<dim3(128, 8, 1), dim3(256), 0, stream>>>(qf, kT_h, kT_l, vbuf, xxT_h, xxT_l);
    gemm_out<<<dim3(3, 16, 16), dim3(256), 0, stream>>>(wp_h, xxT_h, xxT_l, s_p, t_p, out);
}

// Round 4
// 337.206 us; speedup vs baseline: 1.1298x; 1.1298x over previous
//
#include <hip/hip_runtime.h>

typedef _Float16 f16x8 __attribute__((ext_vector_type(8)));
typedef _Float16 f16x4 __attribute__((ext_vector_type(4)));
typedef float f32x4 __attribute__((ext_vector_type(4)));
typedef float f32x16 __attribute__((ext_vector_type(16)));

#define BN_EPS 1e-5f
#define SQRT32 5.656854249492381f
#define LOG2E  1.4426950408889634f

// ---------------------------------------------------------------- prep_x
// x [b][c=384][n=1024] fp32 -> xT_hi/xT_lo [b][n=1024][c=384] fp16 planes.
__global__ __launch_bounds__(256) void prep_x(const float* __restrict__ x,
                                              _Float16* __restrict__ xT_hi,
                                              _Float16* __restrict__ xT_lo) {
    __shared__ float Tx[64][65];
    const int ct = blockIdx.x, nt = blockIdx.y, b = blockIdx.z;
    const int c0 = ct * 64, n0 = nt * 64, t = threadIdx.x;
    {
        int tr = t >> 4, tc = (t & 15) * 4;
        #pragma unroll
        for (int p = 0; p < 4; p++) {
            int r = tr + p * 16;
            float4 v = *(const float4*)(x + ((size_t)(b * 384 + c0 + r)) * 1024 + n0 + tc);
            Tx[r][tc + 0] = v.x; Tx[r][tc + 1] = v.y; Tx[r][tc + 2] = v.z; Tx[r][tc + 3] = v.w;
        }
    }
    __syncthreads();
    {
        int nn = t >> 2, cc = (t & 3) * 16;
        f16x8 h0, h1, l0, l1;
        #pragma unroll
        for (int i = 0; i < 8; i++) {
            float v = Tx[cc + i][nn];
            _Float16 hh = (_Float16)v;
            h0[i] = hh; l0[i] = (_Float16)(v - (float)hh);
        }
        #pragma unroll
        for (int i = 0; i < 8; i++) {
            float v = Tx[cc + 8 + i][nn];
            _Float16 hh = (_Float16)v;
            h1[i] = hh; l1[i] = (_Float16)(v - (float)hh);
        }
        size_t o = ((size_t)(b * 1024 + n0 + nn)) * 384 + c0 + cc;
        *(f16x8*)(xT_hi + o) = h0; *(f16x8*)(xT_hi + o + 8) = h1;
        *(f16x8*)(xT_lo + o) = l0; *(f16x8*)(xT_lo + o + 8) = l1;
    }
}

// ---------------------------------------------------------------- prep_w
__global__ __launch_bounds__(256) void prep_w(const float* __restrict__ wq,
                                              const float* __restrict__ wk,
                                              const float* __restrict__ wv,
                                              const float* __restrict__ wp,
                                              _Float16* __restrict__ wqk_h,
                                              _Float16* __restrict__ wqk_l,
                                              _Float16* __restrict__ wv_h,
                                              _Float16* __restrict__ wp_h) {
    const int NQK = 512 * 384, NV = 1024 * 384, NP = 384 * 1024;
    int i = blockIdx.x * 256 + threadIdx.x;
    if (i < NQK) {
        int o = i / 384, c = i - o * 384;
        float v = (o < 256) ? wq[o * 384 + c] : wk[(o - 256) * 384 + c];
        _Float16 hh = (_Float16)v;
        wqk_h[i] = hh; wqk_l[i] = (_Float16)(v - (float)hh);
    } else if (i < NQK + NV) {
        wv_h[i - NQK] = (_Float16)wv[i - NQK];
    } else if (i < NQK + NV + NP) {
        wp_h[i - NQK - NV] = (_Float16)wp[i - NQK - NV];
    }
}

// ---------------------------------------------------------------- prep_st
__global__ __launch_bounds__(256) void prep_st(const float* __restrict__ bnq,
                                               const float* __restrict__ bnk,
                                               const float* __restrict__ bnv,
                                               const float* __restrict__ bnp,
                                               float* __restrict__ s_qkv, float* __restrict__ t_qkv,
                                               float* __restrict__ s_p,   float* __restrict__ t_p) {
    int i = blockIdx.x * blockDim.x + threadIdx.x;
    if (i < 1536) {
        float g, be, m, v;
        if (i < 256)      { int o = i;       g = bnq[o]; be = bnq[256 + o];  m = bnq[512 + o];  v = bnq[768 + o]; }
        else if (i < 512) { int o = i - 256; g = bnk[o]; be = bnk[256 + o];  m = bnk[512 + o];  v = bnk[768 + o]; }
        else              { int o = i - 512; g = bnv[o]; be = bnv[1024 + o]; m = bnv[2048 + o]; v = bnv[3072 + o]; }
        float s = g * rsqrtf(v + BN_EPS);
        float t = be - m * s;
        // fold /scale (= *sqrt(kd)) AND log2(e) (exp2-softmax) into Q's affine
        if (i < 256) { s *= SQRT32 * LOG2E; t *= SQRT32 * LOG2E; }
        s_qkv[i] = s; t_qkv[i] = t;
    } else if (i < 1536 + 384) {
        int o = i - 1536;
        float g = bnp[o], be = bnp[384 + o], m = bnp[768 + o], v = bnp[1152 + o];
        float s = g * rsqrtf(v + BN_EPS);
        s_p[o] = s; t_p[o] = be - m * s;
    }
}

// ---------------------------------------------------------------- gemm_qkv
// D[o][n] = sum_c W[o,c] X[c,n].  bx<4: Q/K rows (3-term hi/lo, fp32 out)
// bx>=4: V rows (1-term, fp16 out).
__global__ __launch_bounds__(256, 2) void gemm_qkv(
    const _Float16* __restrict__ wqk_h, const _Float16* __restrict__ wqk_l,
    const _Float16* __restrict__ wv_h,
    const _Float16* __restrict__ xT_hi, const _Float16* __restrict__ xT_lo,
    const float* __restrict__ S, const float* __restrict__ T,
    float* __restrict__ qf, float* __restrict__ kf, _Float16* __restrict__ vbuf)
{
    __shared__ __align__(16) _Float16 As_h[128 * 40];
    __shared__ __align__(16) _Float16 As_l[128 * 40];
    __shared__ __align__(16) _Float16 Bs_h[128 * 40];
    __shared__ __align__(16) _Float16 Bs_l[128 * 40];
    const int t = threadIdx.x, lane = t & 63, w = t >> 6;
    const int wr = w >> 1, wc = w & 1, l16 = lane & 15, lq = lane >> 4;
    const int bx = blockIdx.x, n0 = blockIdx.y * 128, b = blockIdx.z;
    const bool isv = bx >= 4;
    const int o0 = isv ? (bx - 4) * 128 : bx * 128;
    const _Float16* __restrict__ Ah = isv ? wv_h : wqk_h;

    f32x4 acc[4][4] = {};

    for (int kb = 0; kb < 384; kb += 32) {
        __syncthreads();
        #pragma unroll
        for (int p = 0; p < 2; p++) {
            int g = t + p * 256, row = g >> 2, ch = g & 3;
            *(uint4*)(&As_h[row * 40 + ch * 8]) =
                *(const uint4*)(Ah + (size_t)(o0 + row) * 384 + kb + ch * 8);
        }
        #pragma unroll
        for (int p = 0; p < 2; p++) {
            int g = t + p * 256, row = g >> 2, ch = g & 3;
            *(uint4*)(&Bs_h[row * 40 + ch * 8]) =
                *(const uint4*)(xT_hi + ((size_t)(b * 1024) + n0 + row) * 384 + kb + ch * 8);
        }
        if (!isv) {
            #pragma unroll
            for (int p = 0; p < 2; p++) {
                int g = t + p * 256, row = g >> 2, ch = g & 3;
                *(uint4*)(&As_l[row * 40 + ch * 8]) =
                    *(const uint4*)(wqk_l + (size_t)(o0 + row) * 384 + kb + ch * 8);
            }
            #pragma unroll
            for (int p = 0; p < 2; p++) {
                int g = t + p * 256, row = g >> 2, ch = g & 3;
                *(uint4*)(&Bs_l[row * 40 + ch * 8]) =
                    *(const uint4*)(xT_lo + ((size_t)(b * 1024) + n0 + row) * 384 + kb + ch * 8);
            }
        }
        __syncthreads();

        f16x8 ah[4], bh[4];
        #pragma unroll
        for (int i = 0; i < 4; i++) ah[i] = *(const f16x8*)(&As_h[(wr * 64 + i * 16 + l16) * 40 + lq * 8]);
        #pragma unroll
        for (int j = 0; j < 4; j++) bh[j] = *(const f16x8*)(&Bs_h[(wc * 64 + j * 16 + l16) * 40 + lq * 8]);
        if (!isv) {
            f16x8 al[4], bl[4];
            #pragma unroll
            for (int i = 0; i < 4; i++) al[i] = *(const f16x8*)(&As_l[(wr * 64 + i * 16 + l16) * 40 + lq * 8]);
            #pragma unroll
            for (int j = 0; j < 4; j++) bl[j] = *(const f16x8*)(&Bs_l[(wc * 64 + j * 16 + l16) * 40 + lq * 8]);
            #pragma unroll
            for (int i = 0; i < 4; i++)
                #pragma unroll
                for (int j = 0; j < 4; j++) {
                    acc[i][j] = __builtin_amdgcn_mfma_f32_16x16x32_f16(ah[i], bh[j], acc[i][j], 0, 0, 0);
                    acc[i][j] = __builtin_amdgcn_mfma_f32_16x16x32_f16(al[i], bh[j], acc[i][j], 0, 0, 0);
                    acc[i][j] = __builtin_amdgcn_mfma_f32_16x16x32_f16(ah[i], bl[j], acc[i][j], 0, 0, 0);
                }
        } else {
            #pragma unroll
            for (int i = 0; i < 4; i++)
                #pragma unroll
                for (int j = 0; j < 4; j++)
                    acc[i][j] = __builtin_amdgcn_mfma_f32_16x16x32_f16(ah[i], bh[j], acc[i][j], 0, 0, 0);
        }
    }

    if (!isv) {
        #pragma unroll
        for (int i = 0; i < 4; i++) {
            #pragma unroll
            for (int r = 0; r < 4; r++) {
                int o = o0 + wr * 64 + i * 16 + lq * 4 + r;
                float sc = S[o], sh = T[o];
                float* dst = (o < 256) ? (qf + ((size_t)(b * 256) + o) * 1024)
                                       : (kf + ((size_t)(b * 256) + o - 256) * 1024);
                #pragma unroll
                for (int j = 0; j < 4; j++) {
                    int n = n0 + wc * 64 + j * 16 + l16;
                    dst[n] = acc[i][j][r] * sc + sh;
                }
            }
        }
    } else {
        #pragma unroll
        for (int i = 0; i < 4; i++) {
            #pragma unroll
            for (int r = 0; r < 4; r++) {
                int o = o0 + wr * 64 + i * 16 + lq * 4 + r;
                float sc = S[512 + o], sh = T[512 + o];
                #pragma unroll
                for (int j = 0; j < 4; j++) {
                    int n = n0 + wc * 64 + j * 16 + l16;
                    vbuf[((size_t)(b * 1024) + o) * 1024 + n] = (_Float16)(acc[i][j][r] * sc + sh);
                }
            }
        }
    }
}

// ---------------------------------------------------------------- transpose_k
// kf [b][256][1024] fp32 -> kT_h/kT_l [b][h][n=1024][kd=32] fp16 planes.
__global__ __launch_bounds__(256) void transpose_k(const float* __restrict__ kf,
                                                   _Float16* __restrict__ kT_h,
                                                   _Float16* __restrict__ kT_l) {
    __shared__ float Tk[32][65];
    const int nt = blockIdx.x, h = blockIdx.y, b = blockIdx.z;
    const int n0 = nt * 64, t = threadIdx.x;
    {
        int r = t >> 3, ch = (t & 7) * 8;
        const float* src = kf + ((size_t)(b * 256) + h * 32 + r) * 1024 + n0 + ch;
        float4 v0 = *(const float4*)src, v1 = *(const float4*)(src + 4);
        Tk[r][ch + 0] = v0.x; Tk[r][ch + 1] = v0.y; Tk[r][ch + 2] = v0.z; Tk[r][ch + 3] = v0.w;
        Tk[r][ch + 4] = v1.x; Tk[r][ch + 5] = v1.y; Tk[r][ch + 6] = v1.z; Tk[r][ch + 7] = v1.w;
    }
    __syncthreads();
    {
        int nn = t >> 2, c0 = (t & 3) * 8;
        f16x8 hv, lv;
        #pragma unroll
        for (int i = 0; i < 8; i++) {
            float v = Tk[c0 + i][nn];
            _Float16 hh = (_Float16)v;
            hv[i] = hh; lv[i] = (_Float16)(v - (float)hh);
        }
        size_t o = (((size_t)(b * 8) + h) * 1024 + n0 + nn) * 32 + c0;
        *(f16x8*)(kT_h + o) = hv;
        *(f16x8*)(kT_l + o) = lv;
    }
}

// ---------------------------------------------------------------- attn
// 512 threads = 8 waves; 512 queries/block (64 q/wave in 2 groups of 32).
// Grid (x=bh[128], y=qt[2]) = 256 blocks = 1/CU. K/V re-read amplification = 2x.
// Register-prefetch pipeline: tile kt+1 global->regs issued before compute of kt,
// regs->LDS after compute (2 barriers; loads overlap compute).
// Scores transposed D[key][q] (A=K from LDS, B=Q in regs), 3-term hi/lo, exp2 softmax.
// PV via mfma 32x32x8: P C-layout regs map directly onto B-operand (no repack);
// V LDS reads shared across both q-groups.
__global__ __launch_bounds__(512, 2) void attn(
    const float* __restrict__ qf,
    const _Float16* __restrict__ kT_h, const _Float16* __restrict__ kT_l,
    const _Float16* __restrict__ vbuf,
    _Float16* __restrict__ xxT_h, _Float16* __restrict__ xxT_l)
{
    __shared__ __align__(16) _Float16 Ks_h[64 * 36];
    __shared__ __align__(16) _Float16 Ks_l[64 * 36];
    __shared__ __align__(16) _Float16 Vs[128 * 72];
    const int t = threadIdx.x, lane = t & 63, w = t >> 6;
    const int L = lane & 31, hl = lane >> 5;
    const int bh = blockIdx.x, qt = blockIdx.y;
    const int b = bh >> 3, h = bh & 7;

    // Q B-frags for both q-groups: fp32 -> hi/lo split in-register (once)
    f16x8 bq_h[2][2], bq_l[2][2];
    #pragma unroll
    for (int g = 0; g < 2; g++) {
        int q = qt * 512 + w * 64 + g * 32 + L;
        #pragma unroll
        for (int kh = 0; kh < 2; kh++) {
            #pragma unroll
            for (int i = 0; i < 8; i++) {
                float v = qf[((size_t)(b * 256) + h * 32 + kh * 16 + hl * 8 + i) * 1024 + q];
                _Float16 hh = (_Float16)v;
                bq_h[g][kh][i] = hh;
                bq_l[g][kh][i] = (_Float16)(v - (float)hh);
            }
        }
    }

    f32x16 o_acc[2][4] = {};
    float m_st[2] = {-INFINITY, -INFINITY}, l_st[2] = {0.f, 0.f};

    // staging coords (512 threads)
    const int kpl = t >> 8;                       // 0 = hi plane, 1 = lo plane
    const int kidx = t & 255;
    const int krow = kidx >> 2, kcol = (kidx & 3) * 8;   // K: 64 rows x 32, 16B/thread
    const _Float16* __restrict__ Kp = kpl ? kT_l : kT_h;
    _Float16* __restrict__ KsP = kpl ? Ks_l : Ks_h;

    // ---- preload tile 0 into LDS
    {
        uint4 kx = *(const uint4*)(Kp + ((size_t)(bh * 1024) + krow) * 32 + kcol);
        uint4 vx0, vx1;
        #pragma unroll
        for (int p = 0; p < 2; p++) {
            int g2 = t + p * 512, d = g2 >> 3, kc = g2 & 7;
            uint4 v = *(const uint4*)(vbuf + ((size_t)(b * 1024) + h * 128 + d) * 1024 + kc * 8);
            if (p == 0) vx0 = v; else vx1 = v;
        }
        *(uint4*)(&KsP[krow * 36 + kcol]) = kx;
        #pragma unroll
        for (int p = 0; p < 2; p++) {
            int g2 = t + p * 512, d = g2 >> 3, kc = g2 & 7;
            int kc2 = (kc + (d >> 3)) & 7;
            *(uint4*)(&Vs[d * 72 + kc2 * 8]) = (p == 0) ? vx0 : vx1;
        }
    }
    __syncthreads();

    for (int kt = 0; kt < 16; kt++) {
        // ---- issue prefetch for tile kt+1 (clamped; overlaps compute below)
        int ktn = (kt + 1 < 16) ? kt + 1 : 15;
        uint4 kx = *(const uint4*)(Kp + ((size_t)(bh * 1024) + ktn * 64 + krow) * 32 + kcol);
        uint4 vx0, vx1;
        #pragma unroll
        for (int p = 0; p < 2; p++) {
            int g2 = t + p * 512, d = g2 >> 3, kc = g2 & 7;
            uint4 v = *(const uint4*)(vbuf + ((size_t)(b * 1024) + h * 128 + d) * 1024 + ktn * 64 + kc * 8);
            if (p == 0) vx0 = v; else vx1 = v;
        }

        // ---- compute on tile kt
        f16x4 pfrag[2][8];
        float alpha[2];
        #pragma unroll
        for (int g = 0; g < 2; g++) {
            // scores S^T[key][q], 3-term hi/lo
            f32x16 sA[2];
            #pragma unroll
            for (int sub = 0; sub < 2; sub++) {
                f32x16 c = {};
                #pragma unroll
                for (int kh = 0; kh < 2; kh++) {
                    int kr = (sub * 32 + L) * 36 + kh * 16 + hl * 8;
                    f16x8 k_h = *(const f16x8*)(&Ks_h[kr]);
                    f16x8 k_l = *(const f16x8*)(&Ks_l[kr]);
                    c = __builtin_amdgcn_mfma_f32_32x32x16_f16(k_h, bq_h[g][kh], c, 0, 0, 0);
                    c = __builtin_amdgcn_mfma_f32_32x32x16_f16(k_l, bq_h[g][kh], c, 0, 0, 0);
                    c = __builtin_amdgcn_mfma_f32_32x32x16_f16(k_h, bq_l[g][kh], c, 0, 0, 0);
                }
                sA[sub] = c;
            }
            // online softmax in base-2 (log2e folded into Q's affine)
            float mx = -INFINITY;
            #pragma unroll
            for (int i = 0; i < 16; i++) mx = fmaxf(mx, fmaxf(sA[0][i], sA[1][i]));
            mx = fmaxf(mx, __shfl_xor(mx, 32, 64));
            float mnew = fmaxf(m_st[g], mx);
            alpha[g] = exp2f(m_st[g] - mnew);
            float rs = 0.f;
            #pragma unroll
            for (int sub = 0; sub < 2; sub++)
                #pragma unroll
                for (int qq = 0; qq < 4; qq++)
                    #pragma unroll
                    for (int rr = 0; rr < 4; rr++) {
                        float p = exp2f(sA[sub][qq * 4 + rr] - mnew);
                        rs += p;
                        pfrag[g][sub * 4 + qq][rr] = (_Float16)p;
                    }
            rs += __shfl_xor(rs, 32, 64);
            l_st[g] = l_st[g] * alpha[g] + rs;
            m_st[g] = mnew;
        }
        #pragma unroll
        for (int g = 0; g < 2; g++)
            #pragma unroll
            for (int dt = 0; dt < 4; dt++)
                #pragma unroll
                for (int i = 0; i < 16; i++) o_acc[g][dt][i] *= alpha[g];

        // O[d][q] += V * P  (V LDS read shared by both q-groups)
        #pragma unroll
        for (int slot = 0; slot < 8; slot++) {
            #pragma unroll
            for (int dt = 0; dt < 4; dt++) {
                int kc2 = (slot + dt * 4 + (L >> 3)) & 7;
                f16x4 av = *(const f16x4*)(&Vs[(dt * 32 + L) * 72 + kc2 * 8 + hl * 4]);
                o_acc[0][dt] = __builtin_amdgcn_mfma_f32_32x32x8f16(av, pfrag[0][slot], o_acc[0][dt], 0, 0, 0);
                o_acc[1][dt] = __builtin_amdgcn_mfma_f32_32x32x8f16(av, pfrag[1][slot], o_acc[1][dt], 0, 0, 0);
            }
        }

        // ---- commit prefetched tile to LDS
        if (kt + 1 < 16) {
            __syncthreads();
            *(uint4*)(&KsP[krow * 36 + kcol]) = kx;
            #pragma unroll
            for (int p = 0; p < 2; p++) {
                int g2 = t + p * 512, d = g2 >> 3, kc = g2 & 7;
                int kc2 = (kc + (d >> 3)) & 7;
                *(uint4*)(&Vs[d * 72 + kc2 * 8]) = (p == 0) ? vx0 : vx1;
            }
            __syncthreads();
        }
    }

    // epilogue: normalize, split hi/lo, store xxT[b][n=q][d] (d contiguous)
    #pragma unroll
    for (int g = 0; g < 2; g++) {
        float rl = 1.f / l_st[g];
        int q = qt * 512 + w * 64 + g * 32 + L;
        #pragma unroll
        for (int dt = 0; dt < 4; dt++) {
            #pragma unroll
            for (int gg = 0; gg < 4; gg++) {
                f16x4 hv, lv;
                #pragma unroll
                for (int rr = 0; rr < 4; rr++) {
                    float v = o_acc[g][dt][gg * 4 + rr] * rl;
                    _Float16 hh = (_Float16)v;
                    hv[rr] = hh; lv[rr] = (_Float16)(v - (float)hh);
                }
                size_t o = ((size_t)(b * 1024) + q) * 1024 + h * 128 + dt * 32 + gg * 8 + hl * 4;
                *(f16x4*)(xxT_h + o) = hv;
                *(f16x4*)(xxT_l + o) = lv;
            }
        }
    }
}

// ---------------------------------------------------------------- gemm_out
// out[o][n] = (sum_c Wp[o,c]*xx[c,n]) * s + t, 2-term hi/lo on xx. fp32 out.
__global__ __launch_bounds__(256, 2) void gemm_out(
    const _Float16* __restrict__ wp_h,
    const _Float16* __restrict__ xxT_h, const _Float16* __restrict__ xxT_l,
    const float* __restrict__ S, const float* __restrict__ T,
    float* __restrict__ out)
{
    __shared__ __align__(16) _Float16 As[128 * 40];
    __shared__ __align__(16) _Float16 Bh[64 * 40];
    __shared__ __align__(16) _Float16 Bl[64 * 40];
    const int t = threadIdx.x, lane = t & 63, w = t >> 6;
    const int wr = w >> 1, wc = w & 1, l16 = lane & 15, lq = lane >> 4;
    const int o0 = blockIdx.x * 128, n0 = blockIdx.y * 64, b = blockIdx.z;

    f32x4 acc[4][2] = {};

    for (int kb = 0; kb < 1024; kb += 32) {
        __syncthreads();
        #pragma unroll
        for (int p = 0; p < 2; p++) {
            int g = t + p * 256, row = g >> 2, ch = g & 3;
            *(uint4*)(&As[row * 40 + ch * 8]) =
                *(const uint4*)(wp_h + (size_t)(o0 + row) * 1024 + kb + ch * 8);
        }
        {
            int row = t >> 2, ch = t & 3;
            size_t src = ((size_t)(b * 1024) + n0 + row) * 1024 + kb + ch * 8;
            *(uint4*)(&Bh[row * 40 + ch * 8]) = *(const uint4*)(xxT_h + src);
            *(uint4*)(&Bl[row * 40 + ch * 8]) = *(const uint4*)(xxT_l + src);
        }
        __syncthreads();

        f16x8 a[4], bh[2], bl[2];
        #pragma unroll
        for (int i = 0; i < 4; i++) a[i] = *(const f16x8*)(&As[(wr * 64 + i * 16 + l16) * 40 + lq * 8]);
        #pragma unroll
        for (int j = 0; j < 2; j++) {
            bh[j] = *(const f16x8*)(&Bh[(wc * 32 + j * 16 + l16) * 40 + lq * 8]);
            bl[j] = *(const f16x8*)(&Bl[(wc * 32 + j * 16 + l16) * 40 + lq * 8]);
        }
        #pragma unroll
        for (int i = 0; i < 4; i++)
            #pragma unroll
            for (int j = 0; j < 2; j++) {
                acc[i][j] = __builtin_amdgcn_mfma_f32_16x16x32_f16(a[i], bh[j], acc[i][j], 0, 0, 0);
                acc[i][j] = __builtin_amdgcn_mfma_f32_16x16x32_f16(a[i], bl[j], acc[i][j], 0, 0, 0);
            }
    }

    #pragma unroll
    for (int i = 0; i < 4; i++) {
        #pragma unroll
        for (int r = 0; r < 4; r++) {
            int o = o0 + wr * 64 + i * 16 + lq * 4 + r;
            float sc = S[o], sh = T[o];
            #pragma unroll
            for (int j = 0; j < 2; j++) {
                int n = n0 + wc * 32 + j * 16 + l16;
                out[((size_t)(b * 384) + o) * 1024 + n] = acc[i][j][r] * sc + sh;
            }
        }
    }
}

// ---------------------------------------------------------------- launch

extern "C" void kernel_launch(void* const* d_in, const int* in_sizes, int n_in,
                              void* d_out, int out_size, void* d_ws, size_t ws_size,
                              hipStream_t stream) {
    const float* x   = (const float*)d_in[0];
    const float* wq  = (const float*)d_in[1];
    const float* bnq = (const float*)d_in[2];
    const float* wk  = (const float*)d_in[3];
    const float* bnk = (const float*)d_in[4];
    const float* wv  = (const float*)d_in[5];
    const float* bnv = (const float*)d_in[6];
    const float* wp  = (const float*)d_in[7];
    const float* bnp = (const float*)d_in[8];
    float* out = (float*)d_out;
    (void)in_sizes; (void)n_in; (void)out_size; (void)ws_size;

    char* ws = (char*)d_ws;
    size_t off = 0;
    auto alloc = [&](size_t bytes) {
        void* p = ws + off;
        off = (off + bytes + 255) & ~(size_t)255;
        return p;
    };
    // --- region dead by attn-time (reused for xxT_h) ---
    _Float16* xT_hi = (_Float16*)alloc((size_t)16 * 1024 * 384 * 2);   // 12.58 MB
    _Float16* xT_lo = (_Float16*)alloc((size_t)16 * 1024 * 384 * 2);   // 12.58 MB
    _Float16* wqk_h = (_Float16*)alloc((size_t)512 * 384 * 2);
    _Float16* wqk_l = (_Float16*)alloc((size_t)512 * 384 * 2);
    _Float16* wv_h  = (_Float16*)alloc((size_t)1024 * 384 * 2);
    float*    kf    = (float*)alloc((size_t)16 * 256 * 1024 * 4);      // 16.78 MB
    // region total ~43.5 MB >= xxT_h (33.55 MB)
    _Float16* xxT_h = (_Float16*)d_ws;                                  // alias over dead region
    // --- live buffers ---
    _Float16* wp_h  = (_Float16*)alloc((size_t)384 * 1024 * 2);
    float*    s_qkv = (float*)alloc(1536 * 4);
    float*    t_qkv = (float*)alloc(1536 * 4);
    float*    s_p   = (float*)alloc(384 * 4);
    float*    t_p   = (float*)alloc(384 * 4);
    float*    qf    = (float*)alloc((size_t)16 * 256 * 1024 * 4);      // 16.78 MB
    _Float16* kT_h  = (_Float16*)alloc((size_t)16 * 8 * 1024 * 32 * 2);// 8.39 MB
    _Float16* kT_l  = (_Float16*)alloc((size_t)16 * 8 * 1024 * 32 * 2);// 8.39 MB
    _Float16* vbuf  = (_Float16*)alloc((size_t)16 * 1024 * 1024 * 2);  // 33.55 MB
    _Float16* xxT_l = (_Float16*)alloc((size_t)16 * 1024 * 1024 * 2);  // 33.55 MB

    prep_x<<<dim3(6, 16, 16), dim3(256), 0, stream>>>(x, xT_hi, xT_lo);
    {
        int total = 512 * 384 + 1024 * 384 + 384 * 1024;
        prep_w<<<dim3((total + 255) / 256), dim3(256), 0, stream>>>(wq, wk, wv, wp,
                                                                    wqk_h, wqk_l, wv_h, wp_h);
    }
    prep_st<<<dim3(8), dim3(256), 0, stream>>>(bnq, bnk, bnv, bnp, s_qkv, t_qkv, s_p, t_p);

    gemm_qkv<<<dim3(12, 8, 16), dim3(256), 0, stream>>>(wqk_h, wqk_l, wv_h, xT_hi, xT_lo,
                                                        s_qkv, t_qkv, qf, kf, vbuf);
    transpose_k<<<dim3(16, 8, 16), dim3(256), 0, stream>>>(kf, kT_h, kT_l);
    attn<<<dim3(128, 2, 1), dim3(512), 0, stream>>>(qf, kT_h, kT_l, vbuf, xxT_h, xxT_l);
    gemm_out<<<dim3(3, 16, 16), dim3(256), 0, stream>>>(wp_h, xxT_h, xxT_l, s_p, t_p, out);
}